// Round 2
// baseline (418.697 us; speedup 1.0000x reference)
//
#include <hip/hip_runtime.h>
#include <hip/hip_bf16.h>
#include <math.h>

#define T_TOK   1024
#define D_MODEL 1024
#define H_HEADS 8
#define DKEY    128
#define NKEYS   256
#define TOPK    16
#define TPB     4   // tokens per block in sim/topk kernel

__device__ __forceinline__ float dot4(float4 a, float4 b){
  return a.x*b.x + a.y*b.y + a.z*b.z + a.w*b.w;
}

// ---------------- K1: RMSNorm  x[1024,1024] -> xn[1024,1024] ----------------
__global__ __launch_bounds__(256) void k_rmsnorm(const float* __restrict__ x,
                                                 const float* __restrict__ nw,
                                                 float* __restrict__ xn)
{
  const int t = blockIdx.x, tid = threadIdx.x;
  const float4 v = *(const float4*)(x + (size_t)t*D_MODEL + tid*4);
  float ss = dot4(v, v);
  #pragma unroll
  for (int m = 1; m < 64; m <<= 1) ss += __shfl_xor(ss, m, 64);
  __shared__ float part[4];
  const int lane = tid & 63, wid = tid >> 6;
  if (lane == 0) part[wid] = ss;
  __syncthreads();
  const float tot = part[0] + part[1] + part[2] + part[3];
  const float inv = rsqrtf(tot * (1.0f/(float)D_MODEL) + 1e-5f);
  const float4 w = *(const float4*)(nw + tid*4);
  float4 o;
  o.x = v.x*inv*w.x; o.y = v.y*inv*w.y; o.z = v.z*inv*w.z; o.w = v.w*inv*w.w;
  *(float4*)(xn + (size_t)t*D_MODEL + tid*4) = o;
}

// ---------------- K2: fp32 tiled GEMM  q = xn @ wq  [1024x1024]x[1024x2048] ----
#define TBM 64
#define TBN 64
#define TBK 16
__global__ __launch_bounds__(256) void k_qgemm(const float* __restrict__ A,
                                               const float* __restrict__ B,
                                               float* __restrict__ C)
{
  const int N = 2048, Kd = 1024;
  __shared__ float As[TBK][TBM+4];
  __shared__ float Bs[TBK][TBN+4];
  const int tid = threadIdx.x;
  const int row0 = blockIdx.y * TBM, col0 = blockIdx.x * TBN;
  const int ar = tid >> 2,  ac = (tid & 3) * 4;   // A load: row ar, k ac..ac+3
  const int br = tid >> 4,  bc = (tid & 15) * 4;  // B load: k br, col bc..bc+3
  const int ty = tid >> 4,  tx = tid & 15;        // compute: rows ty*4.., cols tx*4..
  float acc[4][4] = {{0}};
  for (int k0 = 0; k0 < Kd; k0 += TBK){
    const float4 a = *(const float4*)(A + (size_t)(row0+ar)*Kd + k0 + ac);
    const float4 b = *(const float4*)(B + (size_t)(k0+br)*N + col0 + bc);
    As[ac+0][ar] = a.x; As[ac+1][ar] = a.y; As[ac+2][ar] = a.z; As[ac+3][ar] = a.w;
    *(float4*)&Bs[br][bc] = b;
    __syncthreads();
    #pragma unroll
    for (int kk = 0; kk < TBK; kk++){
      const float4 av = *(const float4*)&As[kk][ty*4];
      const float4 bv = *(const float4*)&Bs[kk][tx*4];
      acc[0][0] += av.x*bv.x; acc[0][1] += av.x*bv.y; acc[0][2] += av.x*bv.z; acc[0][3] += av.x*bv.w;
      acc[1][0] += av.y*bv.x; acc[1][1] += av.y*bv.y; acc[1][2] += av.y*bv.z; acc[1][3] += av.y*bv.w;
      acc[2][0] += av.z*bv.x; acc[2][1] += av.z*bv.y; acc[2][2] += av.z*bv.z; acc[2][3] += av.z*bv.w;
      acc[3][0] += av.w*bv.x; acc[3][1] += av.w*bv.y; acc[3][2] += av.w*bv.z; acc[3][3] += av.w*bv.w;
    }
    __syncthreads();
  }
  #pragma unroll
  for (int i = 0; i < 4; i++){
    float4 o; o.x = acc[i][0]; o.y = acc[i][1]; o.z = acc[i][2]; o.w = acc[i][3];
    *(float4*)(C + (size_t)(row0 + ty*4 + i)*N + col0 + tx*4) = o;
  }
}

// ---------------- K3: sims + two-stage top-k -----------------------------------
// grid (H_HEADS, T_TOK/TPB), 256 threads. Wave w handles token t0+w for top-k.
__device__ __forceinline__ void wave_top16(float v[4], int lane, float* tvO, int* tiO)
{
  for (int r = 0; r < 16; r++){
    float bv = v[0]; int bj = 0;
    #pragma unroll
    for (int j = 1; j < 4; j++) if (v[j] > bv){ bv = v[j]; bj = j; }
    int bi = lane*4 + bj;
    #pragma unroll
    for (int m = 1; m < 64; m <<= 1){
      const float ov = __shfl_xor(bv, m, 64);
      const int   oi = __shfl_xor(bi, m, 64);
      if (ov > bv || (ov == bv && oi < bi)){ bv = ov; bi = oi; }
    }
    if (lane == 0){ tvO[r] = bv; tiO[r] = bi; }
    if ((bi >> 2) == lane) v[bi & 3] = -INFINITY;
  }
}

__global__ __launch_bounds__(256) void k_simtopk(const float* __restrict__ Q,
                                                 const float* __restrict__ keys,
                                                 int* __restrict__ fidxO,
                                                 float* __restrict__ gateO)
{
  const int h  = blockIdx.x;
  const int t0 = blockIdx.y * TPB;
  const int tid = threadIdx.x;
  __shared__ float qs[TPB][2*DKEY];
  __shared__ float sims[TPB][2][NKEYS];
  __shared__ float tv[TPB][2][TOPK];
  __shared__ int   ti[TPB][2][TOPK];

  #pragma unroll
  for (int i = 0; i < TPB; i++)
    qs[i][tid] = Q[(size_t)(t0+i)*2048 + h*256 + tid];
  __syncthreads();

  // thread tid == key index k; compute 8 dots (TPB tokens x 2 sub-key sets)
  {
    const int k = tid;
    float acc[TPB][2] = {{0}};
    const float* krow = keys + (size_t)((h*NKEYS + k)*2) * DKEY;
    #pragma unroll
    for (int p = 0; p < 2; p++){
      for (int d = 0; d < DKEY; d += 4){
        const float4 kv = *(const float4*)(krow + p*DKEY + d);
        #pragma unroll
        for (int i = 0; i < TPB; i++){
          const float4 qv = *(const float4*)(&qs[i][p*DKEY + d]);
          acc[i][p] += dot4(kv, qv);
        }
      }
    }
    #pragma unroll
    for (int i = 0; i < TPB; i++){
      sims[i][0][k] = acc[i][0];
      sims[i][1][k] = acc[i][1];
    }
  }
  __syncthreads();

  const int w = tid >> 6, lane = tid & 63;
  // stage-1 top-16 on each sub-key set (wave w -> token t0+w)
  {
    float v0[4], v1[4];
    #pragma unroll
    for (int j = 0; j < 4; j++){
      v0[j] = sims[w][0][lane*4 + j];
      v1[j] = sims[w][1][lane*4 + j];
    }
    wave_top16(v0, lane, &tv[w][0][0], &ti[w][0][0]);
    wave_top16(v1, lane, &tv[w][1][0], &ti[w][1][0]);
  }
  __syncthreads();

  // stage-2: top-16 of the 16x16 cartesian sums. combo c = i0*16 + j0.
  {
    float cv[4];
    const int i0 = lane >> 2;          // (4*lane+j) >> 4
    #pragma unroll
    for (int j = 0; j < 4; j++)
      cv[j] = tv[w][0][i0] + tv[w][1][4*(lane & 3) + j];

    const size_t obase = (size_t)((t0 + w)*H_HEADS + h) * TOPK;
    for (int r = 0; r < 16; r++){
      float bv = cv[0]; int bj = 0;
      #pragma unroll
      for (int j = 1; j < 4; j++) if (cv[j] > bv){ bv = cv[j]; bj = j; }
      int bc = lane*4 + bj;
      #pragma unroll
      for (int m = 1; m < 64; m <<= 1){
        const float ov = __shfl_xor(bv, m, 64);
        const int   oc = __shfl_xor(bc, m, 64);
        if (ov > bv || (ov == bv && oc < bc)){ bv = ov; bc = oc; }
      }
      if (lane == 0){
        fidxO[obase + r] = ti[w][0][bc >> 4] * NKEYS + ti[w][1][bc & 15];
        gateO[obase + r] = bv > 0.0f ? bv : 0.0f;
      }
      if ((bc >> 2) == lane) cv[bc & 3] = -INFINITY;
    }
  }
}

// ---------------- K4: expert gather + dot + gelu + weighted sum ----------------
__global__ __launch_bounds__(256) void k_expert(const float* __restrict__ xn,
                                                const float* __restrict__ ed,
                                                const float* __restrict__ eu,
                                                const int* __restrict__ fidx,
                                                const float* __restrict__ gate,
                                                float* __restrict__ out)
{
  const int t = blockIdx.x, tid = threadIdx.x;
  const int lane = tid & 63, wid = tid >> 6;
  const float4 xv = *(const float4*)(xn + (size_t)t*D_MODEL + tid*4);
  float4 acc = {0.f, 0.f, 0.f, 0.f};
  __shared__ int   sidx[TOPK];
  __shared__ float wred[TOPK][4];
  __shared__ float coeff[TOPK];

  for (int h = 0; h < H_HEADS; ++h){
    const int base = (t*H_HEADS + h)*TOPK;
    if (tid < TOPK) sidx[tid] = fidx[base + tid];
    __syncthreads();
    #pragma unroll
    for (int k = 0; k < TOPK; k++){
      const float4 w = *(const float4*)(ed + (size_t)sidx[k]*D_MODEL + tid*4);
      float p = dot4(xv, w);
      #pragma unroll
      for (int m = 1; m < 64; m <<= 1) p += __shfl_xor(p, m, 64);
      if (lane == 0) wred[k][wid] = p;
    }
    __syncthreads();
    if (tid < TOPK){
      const float hsum = wred[tid][0] + wred[tid][1] + wred[tid][2] + wred[tid][3];
      const float g = 0.5f * hsum * (1.0f + erff(hsum * 0.70710678118654752440f));
      coeff[tid] = g * gate[base + tid];
    }
    __syncthreads();
    #pragma unroll
    for (int k = 0; k < TOPK; k++){
      const float4 w = *(const float4*)(eu + (size_t)sidx[k]*D_MODEL + tid*4);
      const float c = coeff[k];
      acc.x += c*w.x; acc.y += c*w.y; acc.z += c*w.z; acc.w += c*w.w;
    }
    __syncthreads();
  }
  float4 o;
  o.x = acc.x; o.y = acc.y; o.z = acc.z; o.w = acc.w;
  *(float4*)(out + (size_t)t*D_MODEL + tid*4) = o;
}

// ---------------- launch ----------------
extern "C" void kernel_launch(void* const* d_in, const int* in_sizes, int n_in,
                              void* d_out, int out_size, void* d_ws, size_t ws_size,
                              hipStream_t stream)
{
  const float* x      = (const float*)d_in[0];
  const float* norm_w = (const float*)d_in[1];
  const float* wq     = (const float*)d_in[2];
  const float* keys   = (const float*)d_in[3];
  const float* ed     = (const float*)d_in[4];
  const float* eu     = (const float*)d_in[5];
  float* out = (float*)d_out;   // fp32 per reference output dtype

  float* xn  = (float*)d_ws;                       // 1024*1024
  float* q   = xn + (size_t)T_TOK * D_MODEL;       // 1024*2048
  int*  fidx = (int*)(q + (size_t)T_TOK * 2048);   // 1024*8*16
  float* gate = (float*)(fidx + (size_t)T_TOK * H_HEADS * TOPK);

  k_rmsnorm<<<T_TOK, 256, 0, stream>>>(x, norm_w, xn);
  k_qgemm<<<dim3(2048/TBN, 1024/TBM), 256, 0, stream>>>(xn, wq, q);
  k_simtopk<<<dim3(H_HEADS, T_TOK/TPB), 256, 0, stream>>>(q, keys, fidx, gate);
  k_expert<<<T_TOK, 256, 0, stream>>>(xn, ed, eu, fidx, gate, out);
}

// Round 3
// 320.952 us; speedup vs baseline: 1.3045x; 1.3045x over previous
//
#include <hip/hip_runtime.h>
#include <hip/hip_bf16.h>
#include <math.h>

#define T_TOK   1024
#define D_MODEL 1024
#define H_HEADS 8
#define DKEY    128
#define NKEYS   256
#define TOPK    16
#define TPB     4

__device__ __forceinline__ float dot4(float4 a, float4 b){
  return a.x*b.x + a.y*b.y + a.z*b.z + a.w*b.w;
}

// ---------------- K1: RMSNorm ----------------
__global__ __launch_bounds__(256) void k_rmsnorm(const float* __restrict__ x,
                                                 const float* __restrict__ nw,
                                                 float* __restrict__ xn)
{
  const int t = blockIdx.x, tid = threadIdx.x;
  const float4 v = *(const float4*)(x + (size_t)t*D_MODEL + tid*4);
  float ss = dot4(v, v);
  #pragma unroll
  for (int m = 1; m < 64; m <<= 1) ss += __shfl_xor(ss, m, 64);
  __shared__ float part[4];
  const int lane = tid & 63, wid = tid >> 6;
  if (lane == 0) part[wid] = ss;
  __syncthreads();
  const float tot = part[0] + part[1] + part[2] + part[3];
  const float inv = rsqrtf(tot * (1.0f/(float)D_MODEL) + 1e-5f);
  const float4 w = *(const float4*)(nw + tid*4);
  float4 o;
  o.x = v.x*inv*w.x; o.y = v.y*inv*w.y; o.z = v.z*inv*w.z; o.w = v.w*inv*w.w;
  *(float4*)(xn + (size_t)t*D_MODEL + tid*4) = o;
}

// ---------------- K2: fp32 tiled GEMM q = xn @ wq (unchanged) ----------------
#define TBM 64
#define TBN 64
#define TBK 16
__global__ __launch_bounds__(256) void k_qgemm(const float* __restrict__ A,
                                               const float* __restrict__ B,
                                               float* __restrict__ C)
{
  const int N = 2048, Kd = 1024;
  __shared__ float As[TBK][TBM+4];
  __shared__ float Bs[TBK][TBN+4];
  const int tid = threadIdx.x;
  const int row0 = blockIdx.y * TBM, col0 = blockIdx.x * TBN;
  const int ar = tid >> 2,  ac = (tid & 3) * 4;
  const int br = tid >> 4,  bc = (tid & 15) * 4;
  const int ty = tid >> 4,  tx = tid & 15;
  float acc[4][4] = {{0}};
  for (int k0 = 0; k0 < Kd; k0 += TBK){
    const float4 a = *(const float4*)(A + (size_t)(row0+ar)*Kd + k0 + ac);
    const float4 b = *(const float4*)(B + (size_t)(k0+br)*N + col0 + bc);
    As[ac+0][ar] = a.x; As[ac+1][ar] = a.y; As[ac+2][ar] = a.z; As[ac+3][ar] = a.w;
    *(float4*)&Bs[br][bc] = b;
    __syncthreads();
    #pragma unroll
    for (int kk = 0; kk < TBK; kk++){
      const float4 av = *(const float4*)&As[kk][ty*4];
      const float4 bv = *(const float4*)&Bs[kk][tx*4];
      acc[0][0] += av.x*bv.x; acc[0][1] += av.x*bv.y; acc[0][2] += av.x*bv.z; acc[0][3] += av.x*bv.w;
      acc[1][0] += av.y*bv.x; acc[1][1] += av.y*bv.y; acc[1][2] += av.y*bv.z; acc[1][3] += av.y*bv.w;
      acc[2][0] += av.z*bv.x; acc[2][1] += av.z*bv.y; acc[2][2] += av.z*bv.z; acc[2][3] += av.z*bv.w;
      acc[3][0] += av.w*bv.x; acc[3][1] += av.w*bv.y; acc[3][2] += av.w*bv.z; acc[3][3] += av.w*bv.w;
    }
    __syncthreads();
  }
  #pragma unroll
  for (int i = 0; i < 4; i++){
    float4 o; o.x = acc[i][0]; o.y = acc[i][1]; o.z = acc[i][2]; o.w = acc[i][3];
    *(float4*)(C + (size_t)(row0 + ty*4 + i)*N + col0 + tx*4) = o;
  }
}

// ---------------- K3a: sims GEMM  sims[t][h][p][k] = Q_hp[t,:] . keys_hp[k,:] --
// grid (NKEYS/64, T_TOK/64, 16=h*2+p), 256 threads. Coalesced loads, LDS-tiled.
__global__ __launch_bounds__(256) void k_simgemm(const float* __restrict__ Q,
                                                 const float* __restrict__ keys,
                                                 float* __restrict__ sims)
{
  const int hp = blockIdx.z;
  const int t0 = blockIdx.y * 64, kb0 = blockIdx.x * 64;
  const float* A = Q + (size_t)t0*2048 + (hp>>1)*256 + (hp&1)*128;  // row stride 2048
  const float* B = keys + ((size_t)((hp>>1)*NKEYS + kb0)*2 + (hp&1)) * DKEY; // row stride 256
  __shared__ float As[TBK][64+4];
  __shared__ float Bs[TBK][64+4];
  const int tid = threadIdx.x;
  const int ar = tid >> 2, ac = (tid & 3) * 4;   // row (token or key), k-offset
  const int ty = tid >> 4, tx = tid & 15;
  float acc[4][4] = {{0}};
  for (int kd = 0; kd < DKEY; kd += TBK){
    const float4 a = *(const float4*)(A + (size_t)ar*2048 + kd + ac);
    const float4 b = *(const float4*)(B + (size_t)ar*256  + kd + ac);
    As[ac+0][ar] = a.x; As[ac+1][ar] = a.y; As[ac+2][ar] = a.z; As[ac+3][ar] = a.w;
    Bs[ac+0][ar] = b.x; Bs[ac+1][ar] = b.y; Bs[ac+2][ar] = b.z; Bs[ac+3][ar] = b.w;
    __syncthreads();
    #pragma unroll
    for (int kk = 0; kk < TBK; kk++){
      const float4 av = *(const float4*)&As[kk][ty*4];
      const float4 bv = *(const float4*)&Bs[kk][tx*4];
      acc[0][0] += av.x*bv.x; acc[0][1] += av.x*bv.y; acc[0][2] += av.x*bv.z; acc[0][3] += av.x*bv.w;
      acc[1][0] += av.y*bv.x; acc[1][1] += av.y*bv.y; acc[1][2] += av.y*bv.z; acc[1][3] += av.y*bv.w;
      acc[2][0] += av.z*bv.x; acc[2][1] += av.z*bv.y; acc[2][2] += av.z*bv.z; acc[2][3] += av.z*bv.w;
      acc[3][0] += av.w*bv.x; acc[3][1] += av.w*bv.y; acc[3][2] += av.w*bv.z; acc[3][3] += av.w*bv.w;
    }
    __syncthreads();
  }
  // write sims: token row stride = 8*2*256 = 4096
  float* Cb = sims + (size_t)t0*4096 + hp*256 + kb0;
  #pragma unroll
  for (int i = 0; i < 4; i++){
    float4 o; o.x = acc[i][0]; o.y = acc[i][1]; o.z = acc[i][2]; o.w = acc[i][3];
    *(float4*)(Cb + (size_t)(ty*4 + i)*4096 + tx*4) = o;
  }
}

// ---------------- K3b: two-stage top-k from sims ----------------
__device__ __forceinline__ void wave_top16(float v[4], int lane, float* tvO, int* tiO)
{
  for (int r = 0; r < 16; r++){
    float bv = v[0]; int bj = 0;
    #pragma unroll
    for (int j = 1; j < 4; j++) if (v[j] > bv){ bv = v[j]; bj = j; }
    int bi = lane*4 + bj;
    #pragma unroll
    for (int m = 1; m < 64; m <<= 1){
      const float ov = __shfl_xor(bv, m, 64);
      const int   oi = __shfl_xor(bi, m, 64);
      if (ov > bv || (ov == bv && oi < bi)){ bv = ov; bi = oi; }
    }
    if (lane == 0){ tvO[r] = bv; tiO[r] = bi; }
    if ((bi >> 2) == lane) v[bi & 3] = -INFINITY;
  }
}

__global__ __launch_bounds__(256) void k_topk(const float* __restrict__ sims,
                                              int* __restrict__ fidxO,
                                              float* __restrict__ gateO)
{
  const int h  = blockIdx.x;
  const int t0 = blockIdx.y * TPB;
  const int tid = threadIdx.x;
  const int w = tid >> 6, lane = tid & 63;
  const int t = t0 + w;
  __shared__ float tv[TPB][2][TOPK];
  __shared__ int   ti[TPB][2][TOPK];

  float v0[4], v1[4];
  {
    const float4 a = *(const float4*)(sims + (size_t)t*4096 + (h*2+0)*256 + lane*4);
    const float4 b = *(const float4*)(sims + (size_t)t*4096 + (h*2+1)*256 + lane*4);
    v0[0]=a.x; v0[1]=a.y; v0[2]=a.z; v0[3]=a.w;
    v1[0]=b.x; v1[1]=b.y; v1[2]=b.z; v1[3]=b.w;
  }
  wave_top16(v0, lane, &tv[w][0][0], &ti[w][0][0]);
  wave_top16(v1, lane, &tv[w][1][0], &ti[w][1][0]);

  // stage-2 (within-wave; tv/ti written by lane0 of this wave)
  float cv[4];
  const int i0 = lane >> 2;
  #pragma unroll
  for (int j = 0; j < 4; j++)
    cv[j] = tv[w][0][i0] + tv[w][1][4*(lane & 3) + j];

  const size_t obase = (size_t)((t)*H_HEADS + h) * TOPK;
  for (int r = 0; r < 16; r++){
    float bv = cv[0]; int bj = 0;
    #pragma unroll
    for (int j = 1; j < 4; j++) if (cv[j] > bv){ bv = cv[j]; bj = j; }
    int bc = lane*4 + bj;
    #pragma unroll
    for (int m = 1; m < 64; m <<= 1){
      const float ov = __shfl_xor(bv, m, 64);
      const int   oc = __shfl_xor(bc, m, 64);
      if (ov > bv || (ov == bv && oc < bc)){ bv = ov; bc = oc; }
    }
    if (lane == 0){
      fidxO[obase + r] = ti[w][0][bc >> 4] * NKEYS + ti[w][1][bc & 15];
      gateO[obase + r] = bv > 0.0f ? bv : 0.0f;
    }
    if ((bc >> 2) == lane) cv[bc & 3] = -INFINITY;
  }
}

// ---------------- K4: expert gather — batched loads for MLP latency hiding ----
__global__ __launch_bounds__(256) void k_expert(const float* __restrict__ xn,
                                                const float* __restrict__ ed,
                                                const float* __restrict__ eu,
                                                const int* __restrict__ fidx,
                                                const float* __restrict__ gate,
                                                float* __restrict__ out)
{
  const int t = blockIdx.x, tid = threadIdx.x;
  const int lane = tid & 63, wid = tid >> 6;
  const float4 xv = *(const float4*)(xn + (size_t)t*D_MODEL + tid*4);
  float4 acc = {0.f, 0.f, 0.f, 0.f};
  __shared__ int   sidx[TOPK];
  __shared__ float wred[TOPK][4];
  __shared__ float coeff[TOPK];

  for (int h = 0; h < H_HEADS; ++h){
    const int base = (t*H_HEADS + h)*TOPK;
    if (tid < TOPK) sidx[tid] = fidx[base + tid];
    __syncthreads();

    // down-projection: issue ALL 16 row loads, then reduce (keeps 16KB/wave in flight)
    {
      float4 wv[TOPK];
      #pragma unroll
      for (int k = 0; k < TOPK; k++)
        wv[k] = *(const float4*)(ed + (size_t)sidx[k]*D_MODEL + tid*4);
      #pragma unroll
      for (int k = 0; k < TOPK; k++){
        float p = dot4(xv, wv[k]);
        #pragma unroll
        for (int m = 1; m < 64; m <<= 1) p += __shfl_xor(p, m, 64);
        if (lane == 0) wred[k][wid] = p;
      }
    }
    __syncthreads();
    if (tid < TOPK){
      const float hsum = wred[tid][0] + wred[tid][1] + wred[tid][2] + wred[tid][3];
      const float g = 0.5f * hsum * (1.0f + erff(hsum * 0.70710678118654752440f));
      coeff[tid] = g * gate[base + tid];
    }
    __syncthreads();

    // up-projection: same batched pattern
    {
      float4 wv[TOPK];
      #pragma unroll
      for (int k = 0; k < TOPK; k++)
        wv[k] = *(const float4*)(eu + (size_t)sidx[k]*D_MODEL + tid*4);
      #pragma unroll
      for (int k = 0; k < TOPK; k++){
        const float c = coeff[k];
        acc.x += c*wv[k].x; acc.y += c*wv[k].y; acc.z += c*wv[k].z; acc.w += c*wv[k].w;
      }
    }
    __syncthreads();
  }
  *(float4*)(out + (size_t)t*D_MODEL + tid*4) = acc;
}

// ---------------- launch ----------------
extern "C" void kernel_launch(void* const* d_in, const int* in_sizes, int n_in,
                              void* d_out, int out_size, void* d_ws, size_t ws_size,
                              hipStream_t stream)
{
  const float* x      = (const float*)d_in[0];
  const float* norm_w = (const float*)d_in[1];
  const float* wq     = (const float*)d_in[2];
  const float* keys   = (const float*)d_in[3];
  const float* ed     = (const float*)d_in[4];
  const float* eu     = (const float*)d_in[5];
  float* out = (float*)d_out;

  float* xn   = (float*)d_ws;                            // 1024*1024 f32
  float* q    = xn + (size_t)T_TOK * D_MODEL;            // 1024*2048 f32
  int*   fidx = (int*)(q + (size_t)T_TOK * 2048);        // 1024*8*16 i32
  float* gate = (float*)(fidx + (size_t)T_TOK * H_HEADS * TOPK);
  float* sims = gate + (size_t)T_TOK * H_HEADS * TOPK;   // 1024*4096 f32 (16MB)

  k_rmsnorm<<<T_TOK, 256, 0, stream>>>(x, norm_w, xn);
  k_qgemm<<<dim3(2048/TBN, 1024/TBM), 256, 0, stream>>>(xn, wq, q);
  k_simgemm<<<dim3(NKEYS/64, T_TOK/64, 16), 256, 0, stream>>>(q, keys, sims);
  k_topk<<<dim3(H_HEADS, T_TOK/TPB), 256, 0, stream>>>(sims, fidx, gate);
  k_expert<<<T_TOK, 256, 0, stream>>>(xn, ed, eu, fidx, gate, out);
}